// Round 1
// baseline (538.021 us; speedup 1.0000x reference)
//
#include <hip/hip_runtime.h>

#define HW 1024
#define CH_STRIDE (1024*1024)
#define IMG_STRIDE (3*1024*1024)

// DCT-II 8x8 matrix (matches reference _dct_matrix(8), fp64 -> fp32)
constexpr float DCM[8][8] = {
    {0.35355339059327376f, 0.35355339059327376f, 0.35355339059327376f, 0.35355339059327376f,
     0.35355339059327376f, 0.35355339059327376f, 0.35355339059327376f, 0.35355339059327376f},
    {0.49039264020161522f, 0.41573480615127262f, 0.27778511650980111f, 0.09754516100806413f,
    -0.09754516100806413f,-0.27778511650980111f,-0.41573480615127262f,-0.49039264020161522f},
    {0.46193976625564337f, 0.19134171618254489f,-0.19134171618254489f,-0.46193976625564337f,
    -0.46193976625564337f,-0.19134171618254489f, 0.19134171618254489f, 0.46193976625564337f},
    {0.41573480615127262f,-0.09754516100806413f,-0.49039264020161522f,-0.27778511650980111f,
     0.27778511650980111f, 0.49039264020161522f, 0.09754516100806413f,-0.41573480615127262f},
    {0.35355339059327376f,-0.35355339059327376f,-0.35355339059327376f, 0.35355339059327376f,
     0.35355339059327376f,-0.35355339059327376f,-0.35355339059327376f, 0.35355339059327376f},
    {0.27778511650980111f,-0.49039264020161522f, 0.09754516100806413f, 0.41573480615127262f,
    -0.41573480615127262f,-0.09754516100806413f, 0.49039264020161522f,-0.27778511650980111f},
    {0.19134171618254489f,-0.46193976625564337f, 0.46193976625564337f,-0.19134171618254489f,
    -0.19134171618254489f, 0.46193976625564337f,-0.46193976625564337f, 0.19134171618254489f},
    {0.09754516100806413f,-0.27778511650980111f, 0.41573480615127262f,-0.49039264020161522f,
     0.49039264020161522f,-0.41573480615127262f, 0.27778511650980111f,-0.09754516100806413f}
};

// band_of[flat i*8+j] = zigzag_position / 8  (matches reference _zigzag_flat(8))
constexpr int BAND[64] = {
    0,0,0,0,1,1,3,3,
    0,0,0,1,2,3,3,5,
    0,1,1,2,3,3,5,5,
    1,1,2,3,3,5,5,6,
    1,2,2,4,4,5,6,6,
    2,2,4,4,5,6,6,7,
    2,4,4,5,6,7,7,7,
    4,4,6,6,7,7,7,7
};

__device__ __forceinline__ float wave_reduce_add(float v) {
    #pragma unroll
    for (int off = 32; off > 0; off >>= 1)
        v += __shfl_xor(v, off, 64);
    return v;
}

__global__ __launch_bounds__(256) void dct_band_kernel(
    const float* __restrict__ images,
    double* __restrict__ sums,      // [32][8]
    double* __restrict__ sumsq,     // [32][8]
    unsigned int* __restrict__ maxbits)
{
    const int tid = threadIdx.x;
    const int wg = blockIdx.x;
    const int img = wg >> 6;            // 64 WGs per image
    const int chunk = wg & 63;
    const int t = chunk * 256 + tid;    // block index within image [0,16384)
    const int by = t >> 7;              // 128 blocks per row
    const int bx = t & 127;

    const float* base = images + (size_t)img * IMG_STRIDE + (size_t)(by * 8) * HW + bx * 8;

    float lum[8][8];
    float fmax_v = 0.0f;
    #pragma unroll
    for (int r = 0; r < 8; ++r) {
        const float4* pr = (const float4*)(base + (size_t)r * HW);
        const float4* pg = (const float4*)(base + CH_STRIDE + (size_t)r * HW);
        const float4* pb = (const float4*)(base + 2 * CH_STRIDE + (size_t)r * HW);
        float4 R0 = pr[0], R1 = pr[1];
        float4 G0 = pg[0], G1 = pg[1];
        float4 B0 = pb[0], B1 = pb[1];
        float rr[8] = {R0.x, R0.y, R0.z, R0.w, R1.x, R1.y, R1.z, R1.w};
        float gg[8] = {G0.x, G0.y, G0.z, G0.w, G1.x, G1.y, G1.z, G1.w};
        float bb[8] = {B0.x, B0.y, B0.z, B0.w, B1.x, B1.y, B1.z, B1.w};
        #pragma unroll
        for (int c = 0; c < 8; ++c) {
            float v = 0.299f * rr[c] + 0.587f * gg[c] + 0.114f * bb[c];
            lum[r][c] = v;
            fmax_v = fmaxf(fmax_v, v);
        }
    }

    // Stage 1: column transform  lum <- D * lum
    #pragma unroll
    for (int j = 0; j < 8; ++j) {
        float col[8];
        #pragma unroll
        for (int i = 0; i < 8; ++i) col[i] = lum[i][j];
        #pragma unroll
        for (int k = 0; k < 8; ++k) {
            float s = 0.0f;
            #pragma unroll
            for (int i = 0; i < 8; ++i) s += DCM[k][i] * col[i];
            lum[k][j] = s;
        }
    }

    // Stage 2: row transform + band accumulate  C = (D*X) * D^T
    float sband[8] = {0,0,0,0,0,0,0,0};
    float qband[8] = {0,0,0,0,0,0,0,0};
    #pragma unroll
    for (int k = 0; k < 8; ++k) {
        float row[8];
        #pragma unroll
        for (int j = 0; j < 8; ++j) row[j] = lum[k][j];
        #pragma unroll
        for (int l = 0; l < 8; ++l) {
            float s = 0.0f;
            #pragma unroll
            for (int j = 0; j < 8; ++j) s += row[j] * DCM[l][j];
            float a = fabsf(s);
            const int b = BAND[k * 8 + l];   // compile-time constant after unroll
            sband[b] += a;
            qband[b] += a * a;
        }
    }

    // Reductions: wave -> LDS -> device atomics
    #pragma unroll
    for (int b = 0; b < 8; ++b) {
        sband[b] = wave_reduce_add(sband[b]);
        qband[b] = wave_reduce_add(qband[b]);
    }
    #pragma unroll
    for (int off = 32; off > 0; off >>= 1)
        fmax_v = fmaxf(fmax_v, __shfl_xor(fmax_v, off, 64));

    __shared__ float lds_s[4][9];
    __shared__ float lds_q[4][8];
    const int wave = tid >> 6;
    const int lane = tid & 63;
    if (lane == 0) {
        #pragma unroll
        for (int b = 0; b < 8; ++b) { lds_s[wave][b] = sband[b]; lds_q[wave][b] = qband[b]; }
        lds_s[wave][8] = fmax_v;
    }
    __syncthreads();
    if (tid < 8) {
        float s = lds_s[0][tid] + lds_s[1][tid] + lds_s[2][tid] + lds_s[3][tid];
        unsafeAtomicAdd(&sums[img * 8 + tid], (double)s);
        float q = lds_q[0][tid] + lds_q[1][tid] + lds_q[2][tid] + lds_q[3][tid];
        unsafeAtomicAdd(&sumsq[img * 8 + tid], (double)q);
    } else if (tid == 8) {
        float m = fmaxf(fmaxf(lds_s[0][8], lds_s[1][8]), fmaxf(lds_s[2][8], lds_s[3][8]));
        atomicMax(maxbits, __float_as_uint(m));
    }
}

__global__ __launch_bounds__(256) void finalize_kernel(
    const double* __restrict__ sums,
    const double* __restrict__ sumsq,
    const unsigned int* __restrict__ maxbits,
    const float* __restrict__ proj_w,   // [512][16]
    const float* __restrict__ proj_b,   // [512]
    float* __restrict__ out)            // [32][512]
{
    const int img = blockIdx.x;
    __shared__ float raw[16];
    const float scale = (__uint_as_float(*maxbits) <= 1.0f) ? 255.0f : 1.0f;
    if (threadIdx.x < 8) {
        const int b = threadIdx.x;
        const double S1 = sums[img * 8 + b];
        const double S2 = sumsq[img * 8 + b];
        const double N = 131072.0;   // 128*128*8
        double mean = S1 / N;
        double var = (S2 - S1 * S1 / N) / (N - 1.0);
        if (var < 0.0) var = 0.0;
        raw[b]     = scale * (float)mean;
        raw[8 + b] = scale * (float)sqrt(var);
    }
    __syncthreads();
    #pragma unroll
    for (int o = 0; o < 2; ++o) {
        const int f = threadIdx.x + o * 256;
        float acc = proj_b[f];
        #pragma unroll
        for (int r = 0; r < 16; ++r)
            acc += raw[r] * proj_w[f * 16 + r];
        out[img * 512 + f] = acc;
    }
}

extern "C" void kernel_launch(void* const* d_in, const int* in_sizes, int n_in,
                              void* d_out, int out_size, void* d_ws, size_t ws_size,
                              hipStream_t stream) {
    const float* images = (const float*)d_in[0];
    // d_in[1] (dct_matrix) and d_in[2] (zigzag_flat) are deterministic; hardcoded above.
    const float* proj_w = (const float*)d_in[3];
    const float* proj_b = (const float*)d_in[4];
    float* out = (float*)d_out;

    double* sums   = (double*)d_ws;            // [32][8]
    double* sumsq  = sums + 32 * 8;            // [32][8]
    unsigned int* maxbits = (unsigned int*)(sumsq + 32 * 8);

    hipMemsetAsync(d_ws, 0, 2 * 32 * 8 * sizeof(double) + sizeof(unsigned int), stream);
    dct_band_kernel<<<2048, 256, 0, stream>>>(images, sums, sumsq, maxbits);
    finalize_kernel<<<32, 256, 0, stream>>>(sums, sumsq, maxbits, proj_w, proj_b, out);
}